// Round 7
// baseline (294.123 us; speedup 1.0000x reference)
//
#include <hip/hip_runtime.h>
#include <cstdint>
#include <cstddef>

#define IN_DIM 128
#define OUT_DIM 128
#define NR 8          // dst ranges == XCD count
#define ACAP 256      // per-range LDS staging capacity per 512-edge chunk (mean 64, +25 sigma)

// native vector types for nontemporal builtins (HIP_vector_type is rejected)
typedef int vint4 __attribute__((ext_vector_type(4)));
typedef float vfloat2 __attribute__((ext_vector_type(2)));

// bf16 helpers (OCP bf16 = top 16 bits of fp32, RNE)
__device__ __forceinline__ unsigned short f2bf(float f) {
  unsigned int u = __float_as_uint(f);
  u = (u + 0x7FFFu + ((u >> 16) & 1u)) >> 16;
  return (unsigned short)u;
}
__device__ __forceinline__ float bf_lo(unsigned int v) { return __uint_as_float(v << 16); }
__device__ __forceinline__ float bf_hi(unsigned int v) { return __uint_as_float(v & 0xFFFF0000u); }

// ------------------------------------------------------------------ utils
__global__ void k_zero_i32(int* __restrict__ p, int n) {
  int i = blockIdx.x * blockDim.x + threadIdx.x;
  int st = gridDim.x * blockDim.x;
  for (; i < n; i += st) p[i] = 0;
}

__global__ void k_zero_f32(float* __restrict__ p, long long n) {
  long long i = (long long)blockIdx.x * blockDim.x + threadIdx.x;
  long long st = (long long)gridDim.x * blockDim.x;
  for (; i < n; i += st) p[i] = 0.0f;
}

// ------------------------------------------------------------------ degree histogram (kept for fallback paths)
__global__ void k_hist(const int* __restrict__ dst, int E, int* __restrict__ deg) {
  int i = blockIdx.x * blockDim.x + threadIdx.x;
  int st = gridDim.x * blockDim.x;
  int E4 = E >> 2;
  const vint4* d4 = (const vint4*)dst;
  for (int j = i; j < E4; j += st) {
    vint4 v = __builtin_nontemporal_load(&d4[j]);
    atomicAdd(&deg[v.x], 1);
    atomicAdd(&deg[v.y], 1);
    atomicAdd(&deg[v.z], 1);
    atomicAdd(&deg[v.w], 1);
  }
  for (int j = (E4 << 2) + i; j < E; j += st) {
    atomicAdd(&deg[__builtin_nontemporal_load(&dst[j])], 1);
  }
}

__global__ void k_dinv(const int* __restrict__ deg, float* __restrict__ dinv, int n) {
  int i = blockIdx.x * blockDim.x + threadIdx.x;
  int st = gridDim.x * blockDim.x;
  for (; i < n; i += st) {
    dinv[i] = rsqrtf((float)(deg[i] + 1));  // +1 = self-loop; always > 0
  }
}

// ------------------------------------------------------------------ phase A: bucket edges by dst-range, fused degree histogram.
// Round-6 PMC falsified the eviction theory (nt loads: WRITE 72.6->68.2 MB).
// New model: scattered dword stores pay a ~32B dirty-sector floor (1.6M x 32B
// = 51.2 MB ~ measured 68). Fix = make csr writes spatially dense in time:
// stage per-range in LDS, flush coalesced 4B-packed records to buckets here,
// then scatter per-XCD in phase B where the dirty set (0.8 MB) fits one L2.
__global__ __launch_bounds__(256) void k_bucket(const int* __restrict__ ei, int E, int n,
                                                int* __restrict__ deg,
                                                unsigned int* __restrict__ bkt, int bcap,
                                                int* __restrict__ bcnt,
                                                int2* __restrict__ ovf, int* __restrict__ ocnt) {
  __shared__ unsigned int buf[NR][ACAP];
  __shared__ int cnt[NR];
  __shared__ int base[NR];
  const int rs = (n + NR - 1) / NR;
  const int tid = threadIdx.x;
  const int nChunks = (E + 511) >> 9;

  for (int c = blockIdx.x; c < nChunks; c += gridDim.x) {
    if (tid < NR) cnt[tid] = 0;
    __syncthreads();
    const int i0 = c << 9;
#pragma unroll
    for (int u = 0; u < 2; ++u) {
      int i = i0 + (u << 8) + tid;
      if (i < E) {
        int s = __builtin_nontemporal_load(&ei[i]);
        int d = __builtin_nontemporal_load(&ei[E + i]);
        atomicAdd(&deg[d], 1);
        int r = d / rs;
        int pos = atomicAdd(&cnt[r], 1);
        if (pos < ACAP) {
          buf[r][pos] = ((unsigned int)(d - r * rs) << 17) | (unsigned int)s;
        } else {
          int op = atomicAdd(ocnt, 1);  // statistically never (+25 sigma); correctness net
          ovf[op] = make_int2(s, d);
        }
      }
    }
    __syncthreads();
    if (tid < NR) {
      int c2 = cnt[tid]; if (c2 > ACAP) c2 = ACAP;
      base[tid] = atomicAdd(&bcnt[tid], c2);
    }
    __syncthreads();
#pragma unroll
    for (int r = 0; r < NR; ++r) {
      int c2 = cnt[r]; if (c2 > ACAP) c2 = ACAP;
      int b = base[r];
      unsigned int* dst = bkt + (size_t)r * bcap;
      for (int j = tid; j < c2; j += 256) {
        int idx = b + j;
        if (idx < bcap) {
          __builtin_nontemporal_store(buf[r][j], &dst[idx]);
        } else {  // bucket slab full (can't happen for random input; safety)
          unsigned int w = buf[r][j];
          int op = atomicAdd(ocnt, 1);
          ovf[op] = make_int2((int)(w & 0x1FFFFu), r * rs + (int)(w >> 17));
        }
      }
    }
    __syncthreads();  // protect cnt/buf reuse from lagging flush readers
  }
}

// ------------------------------------------------------------------ phase B: per-XCD scatter bucket -> csr.
// Range r handled only by blocks blockIdx&7==r (round-robin -> XCD r, perf
// heuristic). Dirty set = 0.8 MB csr slice + 50 KB cursor slice in a 4 MB L2
// with only a 0.8 MB sequential bucket read competing: every csr line fills
// all 32 dwords before its single eviction.
__global__ __launch_bounds__(256) void k_scatter_bkt(const unsigned int* __restrict__ bkt, int bcap,
                                                     const int* __restrict__ bcnt,
                                                     int* __restrict__ cursor, int* __restrict__ csr_src,
                                                     int n) {
  const int r = blockIdx.x & 7;
  const int gblk = blockIdx.x >> 3;
  const int nblk = gridDim.x >> 3;
  const int rs = (n + NR - 1) / NR;
  const int lo = r * rs;
  int cr = bcnt[r]; if (cr > bcap) cr = bcap;
  const unsigned int* b = bkt + (size_t)r * bcap;
  for (int i = gblk * 256 + threadIdx.x; i < cr; i += nblk * 256) {
    unsigned int w = __builtin_nontemporal_load(&b[i]);
    int s = (int)(w & 0x1FFFFu);
    int d = lo + (int)(w >> 17);
    int p = atomicAdd(&cursor[d], 1);
    csr_src[p] = s;
  }
}

__global__ void k_scatter_ovf(const int2* __restrict__ ovf, const int* __restrict__ ocnt,
                              int* __restrict__ cursor, int* __restrict__ csr_src) {
  int m = *ocnt;
  for (int i = blockIdx.x * blockDim.x + threadIdx.x; i < m; i += gridDim.x * blockDim.x) {
    int2 e = ovf[i];
    int p = atomicAdd(&cursor[e.y], 1);
    csr_src[p] = e.x;
  }
}

// ------------------------------------------------------------------ scan (exclusive prefix sum of deg -> row_start)
__global__ __launch_bounds__(1024) void k_scan_partial(const int* __restrict__ deg, int* __restrict__ bsum, int n) {
  __shared__ int lds[1024];
  int i = blockIdx.x * 1024 + threadIdx.x;
  int v = (i < n) ? deg[i] : 0;
  lds[threadIdx.x] = v;
  __syncthreads();
  for (int off = 512; off > 0; off >>= 1) {
    if (threadIdx.x < off) lds[threadIdx.x] += lds[threadIdx.x + off];
    __syncthreads();
  }
  if (threadIdx.x == 0) bsum[blockIdx.x] = lds[0];
}

__global__ void k_scan_bsum(const int* __restrict__ bsum, int* __restrict__ boff, int nB) {
  if (blockIdx.x == 0 && threadIdx.x == 0) {
    int run = 0;
    for (int i = 0; i < nB; ++i) { boff[i] = run; run += bsum[i]; }
  }
}

__global__ __launch_bounds__(1024) void k_scan_final(const int* __restrict__ deg, const int* __restrict__ boff,
                                                     int* __restrict__ row_start, int* __restrict__ cursor, int n) {
  __shared__ int lds[1024];
  int i = blockIdx.x * 1024 + threadIdx.x;
  int v = (i < n) ? deg[i] : 0;
  lds[threadIdx.x] = v;
  __syncthreads();
  for (int off = 1; off < 1024; off <<= 1) {
    int t = (threadIdx.x >= off) ? lds[threadIdx.x - off] : 0;
    __syncthreads();
    lds[threadIdx.x] += t;
    __syncthreads();
  }
  if (i < n) {
    int excl = boff[blockIdx.x] + lds[threadIdx.x] - v;
    row_start[i] = excl;
    cursor[i] = excl;
    if (i == n - 1) row_start[n] = excl + v;  // total = E
  }
}

// ------------------------------------------------------------------ legacy single-pass fill (fallback when packing infeasible)
__global__ __launch_bounds__(256) void k_fill_part(const int* __restrict__ ei, int E,
                                                   int* __restrict__ cursor, int* __restrict__ csr_src,
                                                   int n) {
  const int r = blockIdx.x & 7;
  const int gblk = blockIdx.x >> 3;
  const int nblk = gridDim.x >> 3;
  const int rs = (n + 7) >> 3;
  const int lo = r * rs;
  const int hi = (lo + rs < n) ? lo + rs : n;
  const int st = nblk * blockDim.x;
  for (int i = gblk * blockDim.x + threadIdx.x; i < E; i += st) {
    int d = ei[E + i];
    if (d >= lo && d < hi) { int p = atomicAdd(&cursor[d], 1); csr_src[p] = ei[i]; }
  }
}

// ------------------------------------------------------------------ GEMM: gb[r][c] = bf16((x[r] @ W[:,c]) * dinv[r])
// fp32 vector path (no fp32 MFMA on CDNA4). BM=128, BN=128(all), BK=32, 8x8/thread.
__global__ __launch_bounds__(256) void k_gemm_scale(const float* __restrict__ x, const float* __restrict__ W,
                                                    const float* __restrict__ dinv,
                                                    unsigned short* __restrict__ gb, int M) {
  __shared__ float xT[32][128];  // [k][row]  16 KB
  __shared__ float Ws[32][128];  // [k][col]  16 KB
  const int tid = threadIdx.x;
  const int tc = tid & 15;   // col group: cols tc*8 .. tc*8+7
  const int tr = tid >> 4;   // row group: rows tr*8 .. tr*8+7
  const int row0 = blockIdx.x * 128;
  const int lr = tid & 127;          // staging row
  const int lk = (tid >> 7) * 16;    // staging k offset (0 or 16)

  float acc[8][8] = {};

  for (int k0 = 0; k0 < IN_DIM; k0 += 32) {
    int grow = row0 + lr;
    if (grow >= M) grow = M - 1;  // clamp (stores are guarded)
    const float4* xp = (const float4*)(x + (size_t)grow * IN_DIM + k0 + lk);
    float4 a0 = xp[0], a1 = xp[1], a2 = xp[2], a3 = xp[3];
    const float4* wp = (const float4*)(W + (size_t)(k0 + (tid >> 3)) * OUT_DIM + (tid & 7) * 16);
    float4 w0 = wp[0], w1 = wp[1], w2 = wp[2], w3 = wp[3];

    __syncthreads();  // previous tile fully consumed
    xT[lk + 0][lr] = a0.x;  xT[lk + 1][lr] = a0.y;  xT[lk + 2][lr] = a0.z;  xT[lk + 3][lr] = a0.w;
    xT[lk + 4][lr] = a1.x;  xT[lk + 5][lr] = a1.y;  xT[lk + 6][lr] = a1.z;  xT[lk + 7][lr] = a1.w;
    xT[lk + 8][lr] = a2.x;  xT[lk + 9][lr] = a2.y;  xT[lk + 10][lr] = a2.z; xT[lk + 11][lr] = a2.w;
    xT[lk + 12][lr] = a3.x; xT[lk + 13][lr] = a3.y; xT[lk + 14][lr] = a3.z; xT[lk + 15][lr] = a3.w;
    float4* wsp = (float4*)&Ws[tid >> 3][(tid & 7) * 16];
    wsp[0] = w0; wsp[1] = w1; wsp[2] = w2; wsp[3] = w3;
    __syncthreads();

#pragma unroll
    for (int k = 0; k < 32; ++k) {
      float xv[8], wv[8];
      *(float4*)&xv[0] = *(const float4*)&xT[k][tr * 8];
      *(float4*)&xv[4] = *(const float4*)&xT[k][tr * 8 + 4];
      *(float4*)&wv[0] = *(const float4*)&Ws[k][tc * 8];
      *(float4*)&wv[4] = *(const float4*)&Ws[k][tc * 8 + 4];
#pragma unroll
      for (int ii = 0; ii < 8; ++ii)
#pragma unroll
        for (int jj = 0; jj < 8; ++jj)
          acc[ii][jj] = fmaf(xv[ii], wv[jj], acc[ii][jj]);
    }
  }

#pragma unroll
  for (int ii = 0; ii < 8; ++ii) {
    int r = row0 + tr * 8 + ii;
    if (r < M) {
      float s = dinv[r];
      uint4 o;
      o.x = (unsigned int)f2bf(acc[ii][0] * s) | ((unsigned int)f2bf(acc[ii][1] * s) << 16);
      o.y = (unsigned int)f2bf(acc[ii][2] * s) | ((unsigned int)f2bf(acc[ii][3] * s) << 16);
      o.z = (unsigned int)f2bf(acc[ii][4] * s) | ((unsigned int)f2bf(acc[ii][5] * s) << 16);
      o.w = (unsigned int)f2bf(acc[ii][6] * s) | ((unsigned int)f2bf(acc[ii][7] * s) << 16);
      *(uint4*)(gb + (size_t)r * OUT_DIM + tc * 8) = o;
    }
  }
}

// ------------------------------------------------------------------ pull aggregation: one wave per node, lane owns 2 cols (bf16 gathers)
__global__ __launch_bounds__(256) void k_agg(const unsigned short* __restrict__ gb, const int* __restrict__ row_start,
                                             const int* __restrict__ csr_src, const float* __restrict__ dinv,
                                             const float* __restrict__ bias, float* __restrict__ out, int n) {
  const int lane = threadIdx.x & 63;
  const int wave = __builtin_amdgcn_readfirstlane(threadIdx.x >> 6);
  const int wpb = blockDim.x >> 6;
  const int nWaves = gridDim.x * wpb;
  const int c2 = lane * 2;
  const float2 bb = *(const float2*)(bias + c2);

  for (int node = blockIdx.x * wpb + wave; node < n; node += nWaves) {
    const int s = row_start[node];
    const int e = row_start[node + 1];
    unsigned int sv = *(const unsigned int*)(gb + (size_t)node * OUT_DIM + c2);  // self-loop term
    float ax = bf_lo(sv), ay = bf_hi(sv);
    int i = s;
    for (; i + 8 <= e; i += 8) {
      int s0 = csr_src[i + 0], s1 = csr_src[i + 1], s2 = csr_src[i + 2], s3 = csr_src[i + 3];
      int s4 = csr_src[i + 4], s5 = csr_src[i + 5], s6 = csr_src[i + 6], s7 = csr_src[i + 7];
      unsigned int v0 = *(const unsigned int*)(gb + (size_t)s0 * OUT_DIM + c2);
      unsigned int v1 = *(const unsigned int*)(gb + (size_t)s1 * OUT_DIM + c2);
      unsigned int v2 = *(const unsigned int*)(gb + (size_t)s2 * OUT_DIM + c2);
      unsigned int v3 = *(const unsigned int*)(gb + (size_t)s3 * OUT_DIM + c2);
      unsigned int v4 = *(const unsigned int*)(gb + (size_t)s4 * OUT_DIM + c2);
      unsigned int v5 = *(const unsigned int*)(gb + (size_t)s5 * OUT_DIM + c2);
      unsigned int v6 = *(const unsigned int*)(gb + (size_t)s6 * OUT_DIM + c2);
      unsigned int v7 = *(const unsigned int*)(gb + (size_t)s7 * OUT_DIM + c2);
      ax += ((bf_lo(v0) + bf_lo(v1)) + (bf_lo(v2) + bf_lo(v3))) +
            ((bf_lo(v4) + bf_lo(v5)) + (bf_lo(v6) + bf_lo(v7)));
      ay += ((bf_hi(v0) + bf_hi(v1)) + (bf_hi(v2) + bf_hi(v3))) +
            ((bf_hi(v4) + bf_hi(v5)) + (bf_hi(v6) + bf_hi(v7)));
    }
    for (; i < e; ++i) {
      unsigned int v = *(const unsigned int*)(gb + (size_t)csr_src[i] * OUT_DIM + c2);
      ax += bf_lo(v);
      ay += bf_hi(v);
    }
    const float di = dinv[node];
    vfloat2 o;
    o.x = fmaxf(fmaf(ax, di, bb.x), 0.0f);
    o.y = fmaxf(fmaf(ay, di, bb.y), 0.0f);
    __builtin_nontemporal_store(o, (vfloat2*)(out + (size_t)node * OUT_DIM + c2));
  }
}

// ------------------------------------------------------------------ fallback (small ws): atomic scatter
__global__ __launch_bounds__(256) void k_scatter(const int* __restrict__ ei, int E,
                                                 const unsigned short* __restrict__ gb, float* __restrict__ out) {
  const int lane = threadIdx.x & 63;
  const int wave = __builtin_amdgcn_readfirstlane(threadIdx.x >> 6);
  const int wpb = blockDim.x >> 6;
  const int nWaves = gridDim.x * wpb;
  const int c2 = lane * 2;
  for (int e = blockIdx.x * wpb + wave; e < E; e += nWaves) {
    int s = ei[e];
    int d = ei[E + e];
    unsigned int v = *(const unsigned int*)(gb + (size_t)s * OUT_DIM + c2);
    atomicAdd(&out[(size_t)d * OUT_DIM + c2 + 0], bf_lo(v));
    atomicAdd(&out[(size_t)d * OUT_DIM + c2 + 1], bf_hi(v));
  }
}

__global__ void k_finalize(const unsigned short* __restrict__ gb, const float* __restrict__ dinv,
                           const float* __restrict__ bias, float* __restrict__ out, int n) {
  int i = blockIdx.x * blockDim.x + threadIdx.x;
  int st = gridDim.x * blockDim.x;
  int total = n * OUT_DIM;
  for (; i < total; i += st) {
    int node = i >> 7;
    float gv = __uint_as_float(((unsigned int)gb[i]) << 16);
    float v = (out[i] + gv) * dinv[node] + bias[i & 127];
    out[i] = fmaxf(v, 0.0f);
  }
}

// ------------------------------------------------------------------ launch
extern "C" void kernel_launch(void* const* d_in, const int* in_sizes, int n_in,
                              void* d_out, int out_size, void* d_ws, size_t ws_size,
                              hipStream_t stream) {
  const float* x = (const float*)d_in[0];
  const int* ei = (const int*)d_in[1];   // int64 in reference -> delivered as int32
  const float* W = (const float*)d_in[2];
  const float* bias = (const float*)d_in[3];
  float* out = (float*)d_out;

  const int N = in_sizes[0] / IN_DIM;  // 100000
  const int E = in_sizes[1] / 2;       // 1600000

  char* ws = (char*)d_ws;
  size_t off = 0;
  auto alloc = [&](size_t bytes) -> void* {
    void* p = ws + off;
    off += (bytes + 255) & ~(size_t)255;
    return p;
  };
  unsigned short* gb = (unsigned short*)alloc((size_t)N * OUT_DIM * sizeof(unsigned short));  // 25.6 MB
  int* deg = (int*)alloc((size_t)N * sizeof(int));
  float* dinv = (float*)alloc((size_t)N * sizeof(float));
  int* row_start = (int*)alloc((size_t)(N + 1) * sizeof(int));
  int* cursor = (int*)alloc((size_t)N * sizeof(int));
  int* bsum = (int*)alloc(1024 * sizeof(int));
  int* boff = (int*)alloc(1024 * sizeof(int));
  size_t base_need = off;
  int* csr = (int*)alloc((size_t)E * sizeof(int));              // 6.4 MB
  size_t fill_need = off;
  const int bcap = E / NR + E / 64 + 256;                        // +60 sigma slack
  unsigned int* bkt = (unsigned int*)alloc((size_t)NR * bcap * sizeof(unsigned int));  // ~8.1 MB
  int* bmeta = (int*)alloc(16 * sizeof(int));                    // [0..7]=bcnt, [8]=ocnt
  int2* ovf = (int2*)alloc((size_t)E * sizeof(int2));            // 12.8 MB absolute-safety
  size_t bucket_need = off;

  if (ws_size < base_need) return;  // cannot run at all
  const bool full = (ws_size >= fill_need);
  const bool bucketed = (ws_size >= bucket_need) && (N <= (1 << 17));  // packing: 17b src + 14b dstLocal

  const int mBlocks = (N + 127) / 128;
  const int nB = (N + 1023) / 1024;

  if (full && bucketed) {
    k_zero_i32<<<256, 256, 0, stream>>>(deg, N);
    k_zero_i32<<<1, 64, 0, stream>>>(bmeta, 16);
    k_bucket<<<2048, 256, 0, stream>>>(ei, E, N, deg, bkt, bcap, bmeta, ovf, bmeta + 8);
    k_dinv<<<512, 256, 0, stream>>>(deg, dinv, N);
    k_gemm_scale<<<mBlocks, 256, 0, stream>>>(x, W, dinv, gb, N);
    k_scan_partial<<<nB, 1024, 0, stream>>>(deg, bsum, N);
    k_scan_bsum<<<1, 64, 0, stream>>>(bsum, boff, nB);
    k_scan_final<<<nB, 1024, 0, stream>>>(deg, boff, row_start, cursor, N);
    k_scatter_bkt<<<2048, 256, 0, stream>>>(bkt, bcap, bmeta, cursor, csr, N);
    k_scatter_ovf<<<64, 256, 0, stream>>>(ovf, bmeta + 8, cursor, csr);
    k_agg<<<2048, 256, 0, stream>>>(gb, row_start, csr, dinv, bias, out, N);
  } else if (full) {
    k_zero_i32<<<256, 256, 0, stream>>>(deg, N);
    k_hist<<<2048, 256, 0, stream>>>(ei + E, E, deg);
    k_dinv<<<512, 256, 0, stream>>>(deg, dinv, N);
    k_gemm_scale<<<mBlocks, 256, 0, stream>>>(x, W, dinv, gb, N);
    k_scan_partial<<<nB, 1024, 0, stream>>>(deg, bsum, N);
    k_scan_bsum<<<1, 64, 0, stream>>>(bsum, boff, nB);
    k_scan_final<<<nB, 1024, 0, stream>>>(deg, boff, row_start, cursor, N);
    k_fill_part<<<2048, 256, 0, stream>>>(ei, E, cursor, csr, N);
    k_agg<<<2048, 256, 0, stream>>>(gb, row_start, csr, dinv, bias, out, N);
  } else {
    k_zero_i32<<<256, 256, 0, stream>>>(deg, N);
    k_hist<<<2048, 256, 0, stream>>>(ei + E, E, deg);
    k_dinv<<<512, 256, 0, stream>>>(deg, dinv, N);
    k_gemm_scale<<<mBlocks, 256, 0, stream>>>(x, W, dinv, gb, N);
    k_zero_f32<<<2048, 256, 0, stream>>>(out, (long long)N * OUT_DIM);
    k_scatter<<<4096, 256, 0, stream>>>(ei, E, gb, out);
    k_finalize<<<2048, 256, 0, stream>>>(gb, dinv, bias, out, N);
  }
}